// Round 3
// baseline (1579.111 us; speedup 1.0000x reference)
//
#include <hip/hip_runtime.h>

#define N_NODES 50000
#define N_EDGES 600000
#define IN_DIM 9
#define HID 128
#define OUT_DIM 6

// ---------------------------------------------------------------------------
// Packed fp32x2 global atomic add (gfx90a+), scalar fallback.
// ---------------------------------------------------------------------------
__device__ __forceinline__ void atomic_add_f32x2(float* addr, float x, float y) {
#if __has_builtin(__builtin_amdgcn_global_atomic_fadd_v2f32)
    typedef float v2f __attribute__((ext_vector_type(2)));
    v2f v; v.x = x; v.y = y;
    __builtin_amdgcn_global_atomic_fadd_v2f32((v2f*)addr, v);
#else
    atomicAdd(addr + 0, x);
    atomicAdd(addr + 1, y);
#endif
}

// ---------------------------------------------------------------------------
// Kernel A: node encoder  h_v = relu(x @ W1 + b1) @ W2 + b2     [N,9] -> [N,128]
// 128 threads, 4 nodes per block. Thread t owns output column t.
// ---------------------------------------------------------------------------
__global__ __launch_bounds__(128)
void node_encoder(const float* __restrict__ x,
                  const float* __restrict__ W1,   // [9,128]
                  const float* __restrict__ b1,   // [128]
                  const float* __restrict__ W2,   // [128,128]
                  const float* __restrict__ b2,   // [128]
                  float* __restrict__ hv)         // [N,128]
{
    const int t  = threadIdx.x;
    const int n0 = blockIdx.x * 4;

    __shared__ float xs[4][12];
    __shared__ float h1[4][132];   // row stride 528B (multiple of 16B)

    if (t < 4 * IN_DIM) {
        int n = t / IN_DIM, k = t % IN_DIM;
        xs[n][k] = x[(n0 + n) * IN_DIM + k];
    }
    __syncthreads();

    float w[IN_DIM];
#pragma unroll
    for (int k = 0; k < IN_DIM; ++k) w[k] = W1[k * HID + t];
    const float bb1 = b1[t];
#pragma unroll
    for (int n = 0; n < 4; ++n) {
        float s = bb1;
#pragma unroll
        for (int k = 0; k < IN_DIM; ++k) s += xs[n][k] * w[k];
        h1[n][t] = fmaxf(s, 0.f);
    }
    __syncthreads();

    float acc[4] = {0.f, 0.f, 0.f, 0.f};
    for (int k = 0; k < HID; k += 4) {
        const float w0 = W2[(k + 0) * HID + t];
        const float w1 = W2[(k + 1) * HID + t];
        const float w2 = W2[(k + 2) * HID + t];
        const float w3 = W2[(k + 3) * HID + t];
#pragma unroll
        for (int n = 0; n < 4; ++n) {
            const float4 a = *(const float4*)&h1[n][k];
            acc[n] += a.x * w0 + a.y * w1 + a.z * w2 + a.w * w3;
        }
    }
    const float bb2 = b2[t];
#pragma unroll
    for (int n = 0; n < 4; ++n)
        hv[(size_t)(n0 + n) * HID + t] = acc[n] + bb2;
}

// ---------------------------------------------------------------------------
// Kernel B: edge MLP + scatter-add (dominant: ~59 GFLOP)
//   in_e = [hv[row], hv[col], attr]  (257)
//   h_e  = relu(in_e @ W1 + b1) @ W2 + b2
//   agg[col] += h_e          (packed atomic add)
// 128 threads, 16 edges/block. Thread = (edge-group of 4) x (col-group of 4).
// h1s ALIASES ins (ins is dead after layer 1) -> 16.8 KB LDS, 9 blocks/CU.
// ---------------------------------------------------------------------------
#define EPB 16
__global__ __launch_bounds__(128)
void edge_mlp(const float* __restrict__ hv,
              const int* __restrict__ row,
              const int* __restrict__ col,
              const float* __restrict__ eattr,
              const float* __restrict__ W1,   // [257,128]
              const float* __restrict__ b1,   // [128]
              const float* __restrict__ W2,   // [128,128]
              const float* __restrict__ b2,   // [128]
              float* __restrict__ agg)        // [N,128]
{
    const int tid = threadIdx.x;
    const int e0  = blockIdx.x * EPB;

    __shared__ float ins[EPB][260];   // 257 used; row stride 1040B (×16B)
    __shared__ int   rc[2][EPB];      // [0]=row, [1]=col

    // stage indices + attr
    if (tid < 2 * EPB) {
        const int s = tid / EPB, e = tid % EPB;
        rc[s][e] = (s == 0 ? row : col)[e0 + e];
    }
    if (tid < EPB) ins[tid][256] = eattr[e0 + tid];
    __syncthreads();

    // vectorized gather: 16 edges x 2 endpoints x 32 float4-chunks = 1024 chunks
#pragma unroll
    for (int i = tid; i < EPB * 2 * 32; i += 128) {
        const int chunk = i & 31;
        const int src   = (i >> 5) & 1;
        const int e     = i >> 6;
        const float4 v = *(const float4*)&hv[(size_t)rc[src][e] * HID + chunk * 4];
        *(float4*)&ins[e][src * HID + chunk * 4] = v;
    }
    __syncthreads();

    const int cg = tid & 31;         // 32 col-groups of 4 -> 128 cols
    const int eg = tid >> 5;         // 4 edge-groups of 4 -> 16 edges
    const int c0 = cg * 4;
    const int eb = eg * 4;

    // ---- layer 1 ----
    float acc[4][4];
#pragma unroll
    for (int e = 0; e < 4; ++e)
#pragma unroll
        for (int c = 0; c < 4; ++c) acc[e][c] = 0.f;

    for (int k = 0; k < 2 * HID; k += 4) {
        float4 wr0 = *(const float4*)&W1[(k + 0) * HID + c0];
        float4 wr1 = *(const float4*)&W1[(k + 1) * HID + c0];
        float4 wr2 = *(const float4*)&W1[(k + 2) * HID + c0];
        float4 wr3 = *(const float4*)&W1[(k + 3) * HID + c0];
#pragma unroll
        for (int e = 0; e < 4; ++e) {
            const float4 a = *(const float4*)&ins[eb + e][k];
            acc[e][0] += a.x * wr0.x + a.y * wr1.x + a.z * wr2.x + a.w * wr3.x;
            acc[e][1] += a.x * wr0.y + a.y * wr1.y + a.z * wr2.y + a.w * wr3.y;
            acc[e][2] += a.x * wr0.z + a.y * wr1.z + a.z * wr2.z + a.w * wr3.z;
            acc[e][3] += a.x * wr0.w + a.y * wr1.w + a.z * wr2.w + a.w * wr3.w;
        }
    }
    {   // attr row (k = 256)
        const float4 wa = *(const float4*)&W1[256 * HID + c0];
#pragma unroll
        for (int e = 0; e < 4; ++e) {
            const float a = ins[eb + e][256];
            acc[e][0] += a * wa.x; acc[e][1] += a * wa.y;
            acc[e][2] += a * wa.z; acc[e][3] += a * wa.w;
        }
    }

    // ins is now dead; overlay h1s on it (barrier separates lifetimes)
    __syncthreads();
    float (*h1s)[132] = (float (*)[132])&ins[0][0];
    {
        const float4 bb = *(const float4*)&b1[c0];
#pragma unroll
        for (int e = 0; e < 4; ++e) {
            h1s[eb + e][c0 + 0] = fmaxf(acc[e][0] + bb.x, 0.f);
            h1s[eb + e][c0 + 1] = fmaxf(acc[e][1] + bb.y, 0.f);
            h1s[eb + e][c0 + 2] = fmaxf(acc[e][2] + bb.z, 0.f);
            h1s[eb + e][c0 + 3] = fmaxf(acc[e][3] + bb.w, 0.f);
        }
    }
    __syncthreads();

    // ---- layer 2 ----
    float acc2[4][4];
#pragma unroll
    for (int e = 0; e < 4; ++e)
#pragma unroll
        for (int c = 0; c < 4; ++c) acc2[e][c] = 0.f;

    for (int k = 0; k < HID; k += 4) {
        float4 wr0 = *(const float4*)&W2[(k + 0) * HID + c0];
        float4 wr1 = *(const float4*)&W2[(k + 1) * HID + c0];
        float4 wr2 = *(const float4*)&W2[(k + 2) * HID + c0];
        float4 wr3 = *(const float4*)&W2[(k + 3) * HID + c0];
#pragma unroll
        for (int e = 0; e < 4; ++e) {
            const float4 a = *(const float4*)&h1s[eb + e][k];
            acc2[e][0] += a.x * wr0.x + a.y * wr1.x + a.z * wr2.x + a.w * wr3.x;
            acc2[e][1] += a.x * wr0.y + a.y * wr1.y + a.z * wr2.y + a.w * wr3.y;
            acc2[e][2] += a.x * wr0.z + a.y * wr1.z + a.z * wr2.z + a.w * wr3.z;
            acc2[e][3] += a.x * wr0.w + a.y * wr1.w + a.z * wr2.w + a.w * wr3.w;
        }
    }

    const float4 bb2 = *(const float4*)&b2[c0];
#pragma unroll
    for (int e = 0; e < 4; ++e) {
        float* dst = agg + (size_t)rc[1][eb + e] * HID + c0;
        atomic_add_f32x2(dst + 0, acc2[e][0] + bb2.x, acc2[e][1] + bb2.y);
        atomic_add_f32x2(dst + 2, acc2[e][2] + bb2.z, acc2[e][3] + bb2.w);
    }
}

// ---------------------------------------------------------------------------
// Kernel C: node update  out = relu([hv, agg] @ W1 + b1) @ W2 + b2   [N,256]->[N,6]
// 128 threads, 4 nodes per block.
// ---------------------------------------------------------------------------
__global__ __launch_bounds__(128)
void node_update(const float* __restrict__ hv,
                 const float* __restrict__ agg,
                 const float* __restrict__ W1,   // [256,128]
                 const float* __restrict__ b1,   // [128]
                 const float* __restrict__ W2,   // [128,6]
                 const float* __restrict__ b2,   // [6]
                 float* __restrict__ out)        // [N,6]
{
    const int t  = threadIdx.x;
    const int n0 = blockIdx.x * 4;

    __shared__ float ins[4][260];
    __shared__ float h1[4][132];
    __shared__ float part[4][2][6];

#pragma unroll
    for (int n = 0; n < 4; ++n) {
        ins[n][t]       = hv[(size_t)(n0 + n) * HID + t];
        ins[n][HID + t] = agg[(size_t)(n0 + n) * HID + t];
    }
    __syncthreads();

    float acc[4] = {0.f, 0.f, 0.f, 0.f};
    for (int k = 0; k < 2 * HID; k += 4) {
        const float w0 = W1[(k + 0) * HID + t];
        const float w1 = W1[(k + 1) * HID + t];
        const float w2 = W1[(k + 2) * HID + t];
        const float w3 = W1[(k + 3) * HID + t];
#pragma unroll
        for (int n = 0; n < 4; ++n) {
            const float4 a = *(const float4*)&ins[n][k];
            acc[n] += a.x * w0 + a.y * w1 + a.z * w2 + a.w * w3;
        }
    }
    const float bb1 = b1[t];
#pragma unroll
    for (int n = 0; n < 4; ++n) h1[n][t] = fmaxf(acc[n] + bb1, 0.f);
    __syncthreads();

    float wv[6];
#pragma unroll
    for (int j = 0; j < 6; ++j) wv[j] = W2[t * OUT_DIM + j];

#pragma unroll
    for (int n = 0; n < 4; ++n) {
        const float v = h1[n][t];
        float p[6];
#pragma unroll
        for (int j = 0; j < 6; ++j) p[j] = v * wv[j];
#pragma unroll
        for (int off = 32; off > 0; off >>= 1) {
#pragma unroll
            for (int j = 0; j < 6; ++j) p[j] += __shfl_down(p[j], off);
        }
        if ((t & 63) == 0) {
#pragma unroll
            for (int j = 0; j < 6; ++j) part[n][t >> 6][j] = p[j];
        }
    }
    __syncthreads();

    if (t < 24) {
        const int n = t / 6, j = t % 6;
        out[(size_t)(n0 + n) * OUT_DIM + j] = part[n][0][j] + part[n][1][j] + b2[j];
    }
}

// ---------------------------------------------------------------------------
extern "C" void kernel_launch(void* const* d_in, const int* in_sizes, int n_in,
                              void* d_out, int out_size, void* d_ws, size_t ws_size,
                              hipStream_t stream) {
    const float* node_states = (const float*)d_in[0];
    const int*   edge_index  = (const int*)d_in[1];   // [2, E] int32
    const float* edge_attr   = (const float*)d_in[2];
    const float* ne_W1 = (const float*)d_in[3];
    const float* ne_b1 = (const float*)d_in[4];
    const float* ne_W2 = (const float*)d_in[5];
    const float* ne_b2 = (const float*)d_in[6];
    const float* ee_W1 = (const float*)d_in[7];
    const float* ee_b1 = (const float*)d_in[8];
    const float* ee_W2 = (const float*)d_in[9];
    const float* ee_b2 = (const float*)d_in[10];
    const float* nu_W1 = (const float*)d_in[11];
    const float* nu_b1 = (const float*)d_in[12];
    const float* nu_W2 = (const float*)d_in[13];
    const float* nu_b2 = (const float*)d_in[14];

    float* hv  = (float*)d_ws;                          // [N,128] 25.6 MB
    float* agg = hv + (size_t)N_NODES * HID;            // [N,128] 25.6 MB

    hipMemsetAsync(agg, 0, (size_t)N_NODES * HID * sizeof(float), stream);

    node_encoder<<<N_NODES / 4, 128, 0, stream>>>(
        node_states, ne_W1, ne_b1, ne_W2, ne_b2, hv);

    edge_mlp<<<N_EDGES / EPB, 128, 0, stream>>>(
        hv, edge_index, edge_index + N_EDGES, edge_attr,
        ee_W1, ee_b1, ee_W2, ee_b2, agg);

    node_update<<<N_NODES / 4, 128, 0, stream>>>(
        hv, agg, nu_W1, nu_b1, nu_W2, nu_b2, (float*)d_out);
}